// Round 9
// baseline (115.228 us; speedup 1.0000x reference)
//
#include <hip/hip_runtime.h>

typedef unsigned short u16;
typedef unsigned int u32;
typedef short bf16x8 __attribute__((ext_vector_type(8)));
typedef float f32x4 __attribute__((ext_vector_type(4)));
typedef float f32x16 __attribute__((ext_vector_type(16)));

// float -> bf16 bits, round-to-nearest-even (inputs never NaN here)
__device__ __forceinline__ u16 f2bf(float f) {
  union { float f; unsigned int u; } a; a.f = f;
  unsigned int r = a.u + 0x7FFFu + ((a.u >> 16) & 1u);
  return (u16)(r >> 16);
}
// bf16 bits -> float (exact)
__device__ __forceinline__ float bf2f(u16 b) {
  return __uint_as_float(((u32)b) << 16);
}

// ---- K0: prep. Blocks 0..127: transpose X [192][4096] fp32 -> Xt [4096][192]
// bf16 (32-px tiles via LDS). Blocks 128..181: w_qkv -> bf16. Blocks 182..199:
// w_proj -> bf16. ----
__global__ __launch_bounds__(256) void prep(const float* __restrict__ X,
                                            const float* __restrict__ W,
                                            const float* __restrict__ Wp,
                                            u16* __restrict__ Xt,
                                            u16* __restrict__ Wb,
                                            u16* __restrict__ Wpb) {
  int b = blockIdx.x;
  int t = threadIdx.x;
  if (b < 128) {
    __shared__ float Xl[192 * 33];   // 25344 B, +1 pad
    int p0 = b << 5;
    int px = t & 31, cs = t >> 5;    // 8 c-groups
    #pragma unroll
    for (int i = 0; i < 24; ++i) {
      int c = cs * 24 + i;
      Xl[c * 33 + px] = X[(size_t)c * 4096 + p0 + px];
    }
    __syncthreads();
    int pxo = t >> 3, j0 = (t & 7) * 12;     // 32 px x 96 u32 rows
    u32* Xt32 = (u32*)Xt;
    #pragma unroll
    for (int jj = 0; jj < 12; ++jj) {
      int j = j0 + jj;
      u32 v = ((u32)f2bf(Xl[(2 * j + 1) * 33 + pxo]) << 16) |
              f2bf(Xl[(2 * j) * 33 + pxo]);
      Xt32[(size_t)(p0 + pxo) * 96 + j] = v;
    }
  } else if (b < 182) {
    int idx = (b - 128) * 2048 + t * 8;      // 54 blocks x 2048 = 110592
    #pragma unroll
    for (int i = 0; i < 8; ++i) Wb[idx + i] = f2bf(W[idx + i]);
  } else {
    int idx = (b - 182) * 2048 + t * 8;      // 18 blocks x 2048 = 36864
    #pragma unroll
    for (int i = 0; i < 8; ++i) Wpb[idx + i] = f2bf(Wp[idx + i]);
  }
}

// ---- K1 (and K4): MFMA GEMM. Y[M][4096] = A[M][192] x B[4096][192] (bf16 in,
// K=192 = 6 k-steps). Wave tile 32m x 32n (2x2 frags); block = 4 waves = 32m x
// 128n; grid (32, M/32). MT=1: R4 measured MT=2 B-hoist as a net LOSS (123.4
// vs 121.6 us) -- occupancy beats traffic for tiny L2-resident GEMMs.
// B16 output: bf16 via wave-private LDS re-tile + coalesced u32 stores (u16
// stores / u32 reads: compiler-only fence stops reordering -- same-wave DS ops
// are in-order in HW, so no runtime barrier needed); else fp32 direct. ----
template <bool B16>
__global__ __launch_bounds__(256) void mqkv(const u16* __restrict__ Wb,
                                            const u16* __restrict__ Xt,
                                            void* __restrict__ Yv) {
  __shared__ u16 Sl[4][32 * 32];   // 8 KB, wave-private strips
  int tid = threadIdx.x;
  int wave = tid >> 6, lane = tid & 63;
  int lo = lane & 15, hi = lane >> 4;
  int m0 = blockIdx.y << 5;
  int n0 = (blockIdx.x << 7) + (wave << 5);
  f32x4 zz = {0.f, 0.f, 0.f, 0.f};
  f32x4 acc00 = zz, acc01 = zz, acc10 = zz, acc11 = zz;
  #pragma unroll
  for (int k0 = 0; k0 < 192; k0 += 32) {
    bf16x8 a0 = *(const bf16x8*)(Wb + (size_t)(m0 + lo) * 192 + k0 + hi * 8);
    bf16x8 a1 = *(const bf16x8*)(Wb + (size_t)(m0 + 16 + lo) * 192 + k0 + hi * 8);
    bf16x8 b0 = *(const bf16x8*)(Xt + (size_t)(n0 + lo) * 192 + k0 + hi * 8);
    bf16x8 b1 = *(const bf16x8*)(Xt + (size_t)(n0 + 16 + lo) * 192 + k0 + hi * 8);
    acc00 = __builtin_amdgcn_mfma_f32_16x16x32_bf16(a0, b0, acc00, 0, 0, 0);
    acc01 = __builtin_amdgcn_mfma_f32_16x16x32_bf16(a0, b1, acc01, 0, 0, 0);
    acc10 = __builtin_amdgcn_mfma_f32_16x16x32_bf16(a1, b0, acc10, 0, 0, 0);
    acc11 = __builtin_amdgcn_mfma_f32_16x16x32_bf16(a1, b1, acc11, 0, 0, 0);
  }
  if (B16) {
    u16* S = Sl[wave];
    #pragma unroll
    for (int r = 0; r < 4; ++r) {
      S[(hi * 4 + r) * 32 + lo] = f2bf(acc00[r]);
      S[(hi * 4 + r) * 32 + 16 + lo] = f2bf(acc01[r]);
      S[(16 + hi * 4 + r) * 32 + lo] = f2bf(acc10[r]);
      S[(16 + hi * 4 + r) * 32 + 16 + lo] = f2bf(acc11[r]);
    }
    // compiler fence: u16 stores above must not reorder past u32 reads below
    // (no-alias types). Same-wave LDS is in-order in HW; zero runtime cost.
    asm volatile("" ::: "memory");
    const u32* S32 = (const u32*)S;
    u32* Y32 = (u32*)Yv;            // bf16 Y, row stride 2048 u32
    #pragma unroll
    for (int i = lane; i < 512; i += 64) {
      int row = i >> 4, j = i & 15;
      Y32[(size_t)(m0 + row) * 2048 + (n0 >> 1) + j] = S32[row * 16 + j];
    }
  } else {
    float* Y = (float*)Yv;
    #pragma unroll
    for (int r = 0; r < 4; ++r) {
      Y[(size_t)(m0 + hi * 4 + r) * 4096 + n0 + lo] = acc00[r];
      Y[(size_t)(m0 + hi * 4 + r) * 4096 + n0 + 16 + lo] = acc01[r];
      Y[(size_t)(m0 + 16 + hi * 4 + r) * 4096 + n0 + lo] = acc10[r];
      Y[(size_t)(m0 + 16 + hi * 4 + r) * 4096 + n0 + 16 + lo] = acc11[r];
    }
  }
}

// ---- K2: FUSED depthwise 3x3 + normalize + pack (qkvd round-trip + one
// launch eliminated). 256 blocks x 256 threads; per block: head h, 128-px
// tile (2 image rows). Octet-granular conv (8 px/work-item, ~12 live regs)
// writes bf16 to LDS Cd[72][128]; norm/pack phases read Cd. LDS pooled:
// Il 36864 B staging + Cd 18432 B = 55296 B; Ql/Kl overlay dead Il after the
// conv barrier. Bit-identical numerics: same fmaf order, zero-filled halo
// (fmaf(w,0,s)==s), same conv->bf16->norm rounding sequence. ----
__global__ __launch_bounds__(256) void dwnv(const u16* __restrict__ qkv,
                                            const float* __restrict__ w_dw,
                                            u32* __restrict__ Qh32,
                                            u32* __restrict__ Kh32,
                                            u32* __restrict__ Vt32) {
  __shared__ __align__(16) char pool[36864 + 18432];  // 55296 B
  u16* Il = (u16*)pool;              // [72][4][64] rows y0-1..y0+2 (conv in)
  u16* Cd = (u16*)(pool + 36864);    // [72][128] conv results (bf16)
  u32* Ql = (u32*)pool;              // [128*17] -- overlays dead Il post-conv
  u32* Kl = (u32*)(pool + 8704);     // [128*17]
  int t = threadIdx.x;
  int bid = blockIdx.x;              // 256 blocks
  int h = bid >> 5;
  int p0 = (bid & 31) << 7;          // 128-px tile = rows y0, y0+1
  int y0 = p0 >> 6;
  const float QSC = 0.20412414523193154f * 1.4426950408889634f;  // 24^-0.5*log2(e)

  // ---- stage conv inputs: 72 ch x 4 rows x 8 uint4 (row = 64 bf16 = 8 uint4)
  const uint4* q4 = (const uint4*)qkv;     // channel stride = 512 uint4
  uint4* Il4 = (uint4*)Il;
  for (int i = t; i < 2304; i += 256) {
    int lc = i >> 5;                 // 32 uint4 per channel (4 rows x 8)
    int rr = (i >> 3) & 3;
    int xq = i & 7;
    int y = y0 - 1 + rr;
    int grp = lc / 24, rem = lc - grp * 24;
    int g = grp * 192 + h * 24 + rem;
    uint4 v = {0u, 0u, 0u, 0u};
    if ((unsigned)y < 64u) v = q4[(size_t)g * 512 + y * 8 + xq];
    Il4[lc * 32 + rr * 8 + xq] = v;
  }
  __syncthreads();

  // ---- conv: 72 ch x 2 rows x 8 octets = 1152 work items, 8 px each ----
  for (int i = t; i < 1152; i += 256) {
    int lc = i >> 4;
    int ly = (i >> 3) & 1;           // output row y0+ly; conv rows ly..ly+2
    int x0 = (i & 7) << 3;
    int grp = lc / 24, rem = lc - grp * 24;
    const float* wc = w_dw + (grp * 192 + h * 24 + rem) * 9;
    float acc[8] = {0.f, 0.f, 0.f, 0.f, 0.f, 0.f, 0.f, 0.f};
    #pragma unroll
    for (int i_ = 0; i_ < 3; ++i_) {
      const u16* rp = Il + lc * 256 + (ly + i_) * 64 + x0;
      bf16x8 v8 = *(const bf16x8*)rp;
      float v[10];
      v[0] = (x0 > 0) ? bf2f(rp[-1]) : 0.f;
      #pragma unroll
      for (int k = 0; k < 8; ++k) v[k + 1] = bf2f((u16)v8[k]);
      v[9] = (x0 < 56) ? bf2f(rp[8]) : 0.f;
      #pragma unroll
      for (int j = 0; j < 3; ++j) {
        float wj = wc[i_ * 3 + j];
        #pragma unroll
        for (int xi = 0; xi < 8; ++xi)
          acc[xi] = fmaf(wj, v[xi + j], acc[xi]);
      }
    }
    union { u16 o[8]; uint4 q; } r;
    #pragma unroll
    for (int xi = 0; xi < 8; ++xi) r.o[xi] = f2bf(acc[xi]);
    *(uint4*)(Cd + lc * 128 + ly * 64 + x0) = r.q;
  }
  __syncthreads();   // conv done; Il dead -> Ql/Kl may overlay it

  // ---- norm+pack: waves 0-1 = Q (ch 0..23), waves 2-3 = K (24..47) ----
  {
    int tl = t & 127;
    int cb = (t < 128) ? 0 : 24;
    float v[24];
    float ss = 0.f;
    #pragma unroll
    for (int d = 0; d < 24; ++d) {
      v[d] = bf2f(Cd[(cb + d) * 128 + tl]);
      ss = fmaf(v[d], v[d], ss);
    }
    float isc = ((t < 128) ? QSC : 1.0f) / fmaxf(sqrtf(ss), 1e-12f);
    u32* row = ((t < 128) ? Ql : Kl) + tl * 17;
    #pragma unroll
    for (int j = 0; j < 12; ++j)
      row[j] = ((u32)f2bf(v[2 * j + 1] * isc) << 16) | f2bf(v[2 * j] * isc);
    #pragma unroll
    for (int j = 12; j < 16; ++j) row[j] = 0;
  }
  __syncthreads();

  // ---- global pack (layouts unchanged) ----
  size_t base = ((size_t)(h << 12) + p0) * 16;
  for (int i = t; i < 2048; i += 256) {
    u32 li = (i >> 4) * 17 + (i & 15);
    Qh32[base + i] = Ql[li];
    Kh32[base + i] = Kl[li];
  }
  // V: direct from Cd (ch 48..71); d==24 -> ones; 25..31 -> 0
  const u32* Cd32 = (const u32*)Cd;
  for (int i = t; i < 2048; i += 256) {
    int d = i >> 6, c = i & 63;
    u32 v32;
    if (d < 24)       v32 = Cd32[((48 + d) << 6) + c];
    else if (d == 24) v32 = 0x3F803F80u;   // bf16 1.0 pair -> denominator row
    else              v32 = 0u;
    Vt32[(((size_t)(h * 32 + d)) << 11) + (p0 >> 1) + c] = v32;
  }
}

// in-place exchange: a.lanes[32:63] <-> b.lanes[0:31]
__device__ __forceinline__ void swp32(u32& a, u32& b) {
  asm("v_permlane32_swap_b32 %0, %1" : "+v"(a), "+v"(b));
}

__device__ __forceinline__ bf16x8 mkfrag(u32 a, u32 b, u32 c, u32 d) {
  union { u32 u[4]; bf16x8 v; } x;
  x.u[0] = a; x.u[1] = b; x.u[2] = c; x.u[3] = d;
  return x.v;
}

#define MFMA32(A, B, C) __builtin_amdgcn_mfma_f32_32x32x16_bf16(A, B, C, 0, 0, 0)

// ---- K3: flash attention on 32x32x16 MFMAs. OCCUPANCY PROBE: 64 q per block
// (grid 8 heads x 64 q-groups = 512 blocks = 2 blocks/CU = 4 waves/SIMD, vs
// the prior 128q/1-block/2-waves-per-SIMD). Rationale: the kernel alternates
// MFMA-burst / exp2(trans)-burst / VALU-pack; at 2 waves/SIMD the trans and
// MFMA pipes idle whenever both waves are in the same phase. 4 waves/SIMD
// needs VGPR<=128: oC/qf halve with 64q, and the S-tile halves are computed
// SEQUENTIALLY (s0->exp, then s1->exp) to cut transient pressure (cross-wave
// overlap now covers the lost in-wave ILP). Chip-wide floors: trans 6.8us,
// K/V L2 traffic 256MB/34.5TBps = 7.4us.
//   QK^T: A=K-tile (32k x 16d chunk), B=Q -> S^T frag: col=q=lane&31,
//   row(reg)=key (reg&3)+8*(reg>>2)+4*(lane>>5). exp2 -> trunc-pack pairs ->
//   2 v_permlane32_swap_b32 per 32-key group -> key-LINEAR PV A-frags.
//   PV: B=V^T[d][keys]; C col=d=lane&31; ones-row d=24 = denominator.
// Epilogue: single 64-row pass; Sf row stride 29 (gcd(29,32)=1). ----
__global__ __launch_bounds__(512, 4) void attn(const u16* __restrict__ Qh,
                                               const u16* __restrict__ Kh,
                                               const u16* __restrict__ Vt,
                                               u16* __restrict__ Pt) {
  __shared__ float Sf[8 * 64 * 29];  // 59392 B epilogue staging
  __shared__ u16 Pb[64 * 24];        // 3072 B bf16 out staging
  int tid = threadIdx.x;
  int wave = tid >> 6, lane = tid & 63;
  int l31 = lane & 31, h5 = lane >> 5;
  int b = blockIdx.x;
  int head = b & 7;              // head == XCD (round-robin) -> K/V L2-resident
  int q0 = (b >> 3) << 6;        // 64 queries per block

  const u16* Kb = Kh + ((size_t)head << 17);
  const u16* Vb = Vt + ((size_t)head << 17);

  // Q as B-operand: per q-block of 32 q, two K=16 d-chunks (d24..31 are zero)
  size_t qbase = ((size_t)head << 12) + q0;
  bf16x8 qf[2][2];
  #pragma unroll
  for (int qb = 0; qb < 2; ++qb)
    #pragma unroll
    for (int c = 0; c < 2; ++c)
      qf[qb][c] = *(const bf16x8*)(Qh + ((qbase + qb * 32 + l31) << 5) +
                                   c * 16 + h5 * 8);

  f32x16 oC[2] = {};               // 32q x 32d per q-block (col 24 = denom)

  int kbase = wave << 9;           // 512 keys per wave

  for (int it = 0; it < 8; ++it) { // 8 tiles of 64 keys
    int k0 = kbase + it * 64;
    bf16x8 kf[2][2], vf[4];
    #pragma unroll
    for (int g = 0; g < 2; ++g)
      #pragma unroll
      for (int c = 0; c < 2; ++c)
        kf[g][c] = *(const bf16x8*)(Kb + (((size_t)(k0 + g * 32 + l31)) << 5) +
                                    c * 16 + h5 * 8);
    #pragma unroll
    for (int c4 = 0; c4 < 4; ++c4)
      vf[c4] = *(const bf16x8*)(Vb + (((size_t)l31) << 12) + k0 + c4 * 16 +
                                h5 * 8);
    #pragma unroll
    for (int qb = 0; qb < 2; ++qb) {
      u32 w[16];
      {
        __builtin_amdgcn_s_setprio(1);
        f32x16 s0{};
        s0 = MFMA32(kf[0][0], qf[qb][0], s0);
        s0 = MFMA32(kf[0][1], qf[qb][1], s0);
        __builtin_amdgcn_s_setprio(0);
        #pragma unroll
        for (int r = 0; r < 8; ++r) {
          u32 e0 = __float_as_uint(__builtin_amdgcn_exp2f(s0[2 * r]));
          u32 e1 = __float_as_uint(__builtin_amdgcn_exp2f(s0[2 * r + 1]));
          w[r] = __builtin_amdgcn_perm(e1, e0, 0x07060302u);
        }
      }
      {
        __builtin_amdgcn_s_setprio(1);
        f32x16 s1{};
        s1 = MFMA32(kf[1][0], qf[qb][0], s1);
        s1 = MFMA32(kf[1][1], qf[qb][1], s1);
        __builtin_amdgcn_s_setprio(0);
        #pragma unroll
        for (int r = 0; r < 8; ++r) {
          u32 e2 = __float_as_uint(__builtin_amdgcn_exp2f(s1[2 * r]));
          u32 e3 = __float_as_uint(__builtin_amdgcn_exp2f(s1[2 * r + 1]));
          w[8 + r] = __builtin_amdgcn_perm(e3, e2, 0x07060302u);
        }
      }
      // 2 swaps per 32-key group -> key-linear A-frags (chunks of 16 keys)
      swp32(w[0], w[2]);   swp32(w[1], w[3]);
      swp32(w[4], w[6]);   swp32(w[5], w[7]);
      swp32(w[8], w[10]);  swp32(w[9], w[11]);
      swp32(w[12], w[14]); swp32(w[13], w[15]);
      __builtin_amdgcn_s_setprio(1);
      oC[qb] = MFMA32(mkfrag(w[0], w[1], w[2], w[3]), vf[0], oC[qb]);
      oC[qb] = MFMA32(mkfrag(w[4], w[5], w[6], w[7]), vf[1], oC[qb]);
      oC[qb] = MFMA32(mkfrag(w[8], w[9], w[10], w[11]), vf[2], oC[qb]);
      oC[qb] = MFMA32(mkfrag(w[12], w[13], w[14], w[15]), vf[3], oC[qb]);
      __builtin_amdgcn_s_setprio(0);
    }
  }

  // epilogue: single 64-row pass (q-blocks 0..1).
  const u32* Pb32 = (const u32*)Pb;
  u32* Pt32 = (u32*)Pt;
  {
    // stage fp32 C-layout (num cols 0..23, den col 24) into OWN strip
    int sb = wave * (64 * 29);
    #pragma unroll
    for (int qq = 0; qq < 2; ++qq) {
      #pragma unroll
      for (int r = 0; r < 16; ++r) {
        int row = qq * 32 + (r & 3) + 8 * (r >> 2) + 4 * h5;
        if (l31 < 25) Sf[sb + row * 29 + l31] = oC[qq][r];
      }
    }
    __syncthreads();   // staging complete
    // reduce the 8 K-eighths, normalize, stage bf16 per-pixel rows
    int q = tid & 63;
    int d0 = tid >> 6;             // 0..7
    int base0 = q * 29;
    const int SS = 64 * 29;
    float den = 0.f;
    #pragma unroll
    for (int s = 0; s < 8; ++s) den += Sf[base0 + s * SS + 24];
    float inv = 1.0f / den;
    #pragma unroll
    for (int dp = 0; dp < 3; ++dp) {
      int dd = dp * 8 + d0;
      float v = 0.f;
      #pragma unroll
      for (int s = 0; s < 8; ++s) v += Sf[base0 + s * SS + dd];
      Pb[q * 24 + dd] = f2bf(v * inv);
    }
    __syncthreads();   // Pb complete
    // coalesced u32 stores of the [64 px][12 u32] strip
    for (int i = tid; i < 768; i += 512) {
      int qq = i / 12, j = i - qq * 12;
      Pt32[(size_t)(q0 + qq) * 96 + head * 12 + j] = Pb32[qq * 12 + j];
    }
  }
}

extern "C" void kernel_launch(void* const* d_in, const int* in_sizes, int n_in,
                              void* d_out, int out_size, void* d_ws, size_t ws_size,
                              hipStream_t stream) {
  const float* x      = (const float*)d_in[0];  // [192][4096]
  const float* w_qkv  = (const float*)d_in[1];  // [576][192]
  const float* w_dw   = (const float*)d_in[2];  // [576][9]
  const float* w_proj = (const float*)d_in[3];  // [192][192]
  float* out = (float*)d_out;                   // [192][4096] fp32

  char* ws = (char*)d_ws;
  u16*   qkv    = (u16*)  (ws);                 // 4718592 bf16 (dead after dwnv)
  u16*   Qh     = (u16*)  (ws + 18874368);      // 2097152
  u16*   Kh     = (u16*)  (ws + 20971520);      // 2097152
  u16*   Vt     = (u16*)  (ws + 23068672);      // 2097152  (end 25165824)
  u16*   Xt     = (u16*)  (ws + 25165824);      // 1572864  (bf16 X^T)
  u16*   Wb     = (u16*)  (ws + 26738688);      // 221184
  u16*   Wpb    = (u16*)  (ws + 26959872);      // 73728    (end 27033600)
  u16*   Pt     = (u16*)  (ws + 13107200);      // 1572864  (bf16 attn-out^T)

  // prep: X transpose->bf16 (128) + w_qkv->bf16 (54) + w_proj->bf16 (18)
  prep<<<dim3(200), 256, 0, stream>>>(x, w_qkv, w_proj, Xt, Wb, Wpb);
  // qkv GEMM on MFMA, bf16 out: grid (32 n-tiles, 18 m-tiles)
  mqkv<true><<<dim3(32, 18), 256, 0, stream>>>(Wb, Xt, qkv);
  // FUSED depthwise 3x3 + normalize + pack (spill-safe octet conv via LDS)
  dwnv<<<dim3(256), 256, 0, stream>>>(qkv, w_dw, (u32*)Qh, (u32*)Kh, (u32*)Vt);
  // 512 blocks x 512 threads (2 blocks/CU, 4 waves/SIMD); 64 q per block
  attn<<<dim3(512), 512, 0, stream>>>(Qh, Kh, Vt, Pt);
  // proj GEMM on MFMA, fp32 out: grid (32 n-tiles, 6 m-tiles)
  mqkv<false><<<dim3(32, 6), 256, 0, stream>>>(Wpb, Pt, out);
}

// Round 11
// 110.687 us; speedup vs baseline: 1.0410x; 1.0410x over previous
//
#include <hip/hip_runtime.h>

typedef unsigned short u16;
typedef unsigned int u32;
typedef short bf16x8 __attribute__((ext_vector_type(8)));
typedef float f32x4 __attribute__((ext_vector_type(4)));
typedef float f32x16 __attribute__((ext_vector_type(16)));

// float -> bf16 bits, round-to-nearest-even (inputs never NaN here)
__device__ __forceinline__ u16 f2bf(float f) {
  union { float f; unsigned int u; } a; a.f = f;
  unsigned int r = a.u + 0x7FFFu + ((a.u >> 16) & 1u);
  return (u16)(r >> 16);
}
// bf16 bits -> float (exact)
__device__ __forceinline__ float bf2f(u16 b) {
  return __uint_as_float(((u32)b) << 16);
}

// ---- K0: prep. Blocks 0..127: transpose X [192][4096] fp32 -> Xt [4096][192]
// bf16 (32-px tiles via LDS). Blocks 128..181: w_qkv -> bf16. Blocks 182..199:
// w_proj -> bf16. ----
__global__ __launch_bounds__(256) void prep(const float* __restrict__ X,
                                            const float* __restrict__ W,
                                            const float* __restrict__ Wp,
                                            u16* __restrict__ Xt,
                                            u16* __restrict__ Wb,
                                            u16* __restrict__ Wpb) {
  int b = blockIdx.x;
  int t = threadIdx.x;
  if (b < 128) {
    __shared__ float Xl[192 * 33];   // 25344 B, +1 pad
    int p0 = b << 5;
    int px = t & 31, cs = t >> 5;    // 8 c-groups
    #pragma unroll
    for (int i = 0; i < 24; ++i) {
      int c = cs * 24 + i;
      Xl[c * 33 + px] = X[(size_t)c * 4096 + p0 + px];
    }
    __syncthreads();
    int pxo = t >> 3, j0 = (t & 7) * 12;     // 32 px x 96 u32 rows
    u32* Xt32 = (u32*)Xt;
    #pragma unroll
    for (int jj = 0; jj < 12; ++jj) {
      int j = j0 + jj;
      u32 v = ((u32)f2bf(Xl[(2 * j + 1) * 33 + pxo]) << 16) |
              f2bf(Xl[(2 * j) * 33 + pxo]);
      Xt32[(size_t)(p0 + pxo) * 96 + j] = v;
    }
  } else if (b < 182) {
    int idx = (b - 128) * 2048 + t * 8;      // 54 blocks x 2048 = 110592
    #pragma unroll
    for (int i = 0; i < 8; ++i) Wb[idx + i] = f2bf(W[idx + i]);
  } else {
    int idx = (b - 182) * 2048 + t * 8;      // 18 blocks x 2048 = 36864
    #pragma unroll
    for (int i = 0; i < 8; ++i) Wpb[idx + i] = f2bf(Wp[idx + i]);
  }
}

// ---- K1 (and K4): MFMA GEMM. Y[M][4096] = A[M][192] x B[4096][192] (bf16 in,
// K=192 = 6 k-steps). Wave tile 32m x 32n (2x2 frags); block = 4 waves = 32m x
// 128n; grid (32, M/32). MT=1: R4 measured MT=2 B-hoist as a net LOSS (123.4
// vs 121.6 us) -- occupancy beats traffic for tiny L2-resident GEMMs.
// B16 output: bf16 via wave-private LDS re-tile + coalesced u32 stores (u16
// stores / u32 reads: compiler-only fence stops reordering -- same-wave DS ops
// are in-order in HW, so no runtime barrier needed); else fp32 direct. ----
template <bool B16>
__global__ __launch_bounds__(256) void mqkv(const u16* __restrict__ Wb,
                                            const u16* __restrict__ Xt,
                                            void* __restrict__ Yv) {
  __shared__ u16 Sl[4][32 * 32];   // 8 KB, wave-private strips
  int tid = threadIdx.x;
  int wave = tid >> 6, lane = tid & 63;
  int lo = lane & 15, hi = lane >> 4;
  int m0 = blockIdx.y << 5;
  int n0 = (blockIdx.x << 7) + (wave << 5);
  f32x4 zz = {0.f, 0.f, 0.f, 0.f};
  f32x4 acc00 = zz, acc01 = zz, acc10 = zz, acc11 = zz;
  #pragma unroll
  for (int k0 = 0; k0 < 192; k0 += 32) {
    bf16x8 a0 = *(const bf16x8*)(Wb + (size_t)(m0 + lo) * 192 + k0 + hi * 8);
    bf16x8 a1 = *(const bf16x8*)(Wb + (size_t)(m0 + 16 + lo) * 192 + k0 + hi * 8);
    bf16x8 b0 = *(const bf16x8*)(Xt + (size_t)(n0 + lo) * 192 + k0 + hi * 8);
    bf16x8 b1 = *(const bf16x8*)(Xt + (size_t)(n0 + 16 + lo) * 192 + k0 + hi * 8);
    acc00 = __builtin_amdgcn_mfma_f32_16x16x32_bf16(a0, b0, acc00, 0, 0, 0);
    acc01 = __builtin_amdgcn_mfma_f32_16x16x32_bf16(a0, b1, acc01, 0, 0, 0);
    acc10 = __builtin_amdgcn_mfma_f32_16x16x32_bf16(a1, b0, acc10, 0, 0, 0);
    acc11 = __builtin_amdgcn_mfma_f32_16x16x32_bf16(a1, b1, acc11, 0, 0, 0);
  }
  if (B16) {
    u16* S = Sl[wave];
    #pragma unroll
    for (int r = 0; r < 4; ++r) {
      S[(hi * 4 + r) * 32 + lo] = f2bf(acc00[r]);
      S[(hi * 4 + r) * 32 + 16 + lo] = f2bf(acc01[r]);
      S[(16 + hi * 4 + r) * 32 + lo] = f2bf(acc10[r]);
      S[(16 + hi * 4 + r) * 32 + 16 + lo] = f2bf(acc11[r]);
    }
    // compiler fence: u16 stores above must not reorder past u32 reads below
    // (no-alias types). Same-wave LDS is in-order in HW; zero runtime cost.
    asm volatile("" ::: "memory");
    const u32* S32 = (const u32*)S;
    u32* Y32 = (u32*)Yv;            // bf16 Y, row stride 2048 u32
    #pragma unroll
    for (int i = lane; i < 512; i += 64) {
      int row = i >> 4, j = i & 15;
      Y32[(size_t)(m0 + row) * 2048 + (n0 >> 1) + j] = S32[row * 16 + j];
    }
  } else {
    float* Y = (float*)Yv;
    #pragma unroll
    for (int r = 0; r < 4; ++r) {
      Y[(size_t)(m0 + hi * 4 + r) * 4096 + n0 + lo] = acc00[r];
      Y[(size_t)(m0 + hi * 4 + r) * 4096 + n0 + 16 + lo] = acc01[r];
      Y[(size_t)(m0 + 16 + hi * 4 + r) * 4096 + n0 + lo] = acc10[r];
      Y[(size_t)(m0 + 16 + hi * 4 + r) * 4096 + n0 + 16 + lo] = acc11[r];
    }
  }
}

// ---- K2: FUSED depthwise 3x3 + normalize + pack (qkvd round-trip + one
// launch eliminated). 256 blocks x 256 threads; per block: head h, 128-px
// tile (2 image rows). Octet-granular conv (8 px/work-item, ~12 live regs)
// writes bf16 to LDS Cd[72][128]; norm/pack phases read Cd. LDS pooled:
// Il 36864 B staging + Cd 18432 B = 55296 B; Ql/Kl overlay dead Il after the
// conv barrier. Bit-identical numerics: same fmaf order, zero-filled halo
// (fmaf(w,0,s)==s), same conv->bf16->norm rounding sequence. ----
__global__ __launch_bounds__(256) void dwnv(const u16* __restrict__ qkv,
                                            const float* __restrict__ w_dw,
                                            u32* __restrict__ Qh32,
                                            u32* __restrict__ Kh32,
                                            u32* __restrict__ Vt32) {
  __shared__ __align__(16) char pool[36864 + 18432];  // 55296 B
  u16* Il = (u16*)pool;              // [72][4][64] rows y0-1..y0+2 (conv in)
  u16* Cd = (u16*)(pool + 36864);    // [72][128] conv results (bf16)
  u32* Ql = (u32*)pool;              // [128*17] -- overlays dead Il post-conv
  u32* Kl = (u32*)(pool + 8704);     // [128*17]
  int t = threadIdx.x;
  int bid = blockIdx.x;              // 256 blocks
  int h = bid >> 5;
  int p0 = (bid & 31) << 7;          // 128-px tile = rows y0, y0+1
  int y0 = p0 >> 6;
  const float QSC = 0.20412414523193154f * 1.4426950408889634f;  // 24^-0.5*log2(e)

  // ---- stage conv inputs: 72 ch x 4 rows x 8 uint4 (row = 64 bf16 = 8 uint4)
  const uint4* q4 = (const uint4*)qkv;     // channel stride = 512 uint4
  uint4* Il4 = (uint4*)Il;
  for (int i = t; i < 2304; i += 256) {
    int lc = i >> 5;                 // 32 uint4 per channel (4 rows x 8)
    int rr = (i >> 3) & 3;
    int xq = i & 7;
    int y = y0 - 1 + rr;
    int grp = lc / 24, rem = lc - grp * 24;
    int g = grp * 192 + h * 24 + rem;
    uint4 v = {0u, 0u, 0u, 0u};
    if ((unsigned)y < 64u) v = q4[(size_t)g * 512 + y * 8 + xq];
    Il4[lc * 32 + rr * 8 + xq] = v;
  }
  __syncthreads();

  // ---- conv: 72 ch x 2 rows x 8 octets = 1152 work items, 8 px each ----
  for (int i = t; i < 1152; i += 256) {
    int lc = i >> 4;
    int ly = (i >> 3) & 1;           // output row y0+ly; conv rows ly..ly+2
    int x0 = (i & 7) << 3;
    int grp = lc / 24, rem = lc - grp * 24;
    const float* wc = w_dw + (grp * 192 + h * 24 + rem) * 9;
    float acc[8] = {0.f, 0.f, 0.f, 0.f, 0.f, 0.f, 0.f, 0.f};
    #pragma unroll
    for (int i_ = 0; i_ < 3; ++i_) {
      const u16* rp = Il + lc * 256 + (ly + i_) * 64 + x0;
      bf16x8 v8 = *(const bf16x8*)rp;
      float v[10];
      v[0] = (x0 > 0) ? bf2f(rp[-1]) : 0.f;
      #pragma unroll
      for (int k = 0; k < 8; ++k) v[k + 1] = bf2f((u16)v8[k]);
      v[9] = (x0 < 56) ? bf2f(rp[8]) : 0.f;
      #pragma unroll
      for (int j = 0; j < 3; ++j) {
        float wj = wc[i_ * 3 + j];
        #pragma unroll
        for (int xi = 0; xi < 8; ++xi)
          acc[xi] = fmaf(wj, v[xi + j], acc[xi]);
      }
    }
    union { u16 o[8]; uint4 q; } r;
    #pragma unroll
    for (int xi = 0; xi < 8; ++xi) r.o[xi] = f2bf(acc[xi]);
    *(uint4*)(Cd + lc * 128 + ly * 64 + x0) = r.q;
  }
  __syncthreads();   // conv done; Il dead -> Ql/Kl may overlay it

  // ---- norm+pack: waves 0-1 = Q (ch 0..23), waves 2-3 = K (24..47) ----
  {
    int tl = t & 127;
    int cb = (t < 128) ? 0 : 24;
    float v[24];
    float ss = 0.f;
    #pragma unroll
    for (int d = 0; d < 24; ++d) {
      v[d] = bf2f(Cd[(cb + d) * 128 + tl]);
      ss = fmaf(v[d], v[d], ss);
    }
    float isc = ((t < 128) ? QSC : 1.0f) / fmaxf(sqrtf(ss), 1e-12f);
    u32* row = ((t < 128) ? Ql : Kl) + tl * 17;
    #pragma unroll
    for (int j = 0; j < 12; ++j)
      row[j] = ((u32)f2bf(v[2 * j + 1] * isc) << 16) | f2bf(v[2 * j] * isc);
    #pragma unroll
    for (int j = 12; j < 16; ++j) row[j] = 0;
  }
  __syncthreads();

  // ---- global pack (layouts unchanged) ----
  size_t base = ((size_t)(h << 12) + p0) * 16;
  for (int i = t; i < 2048; i += 256) {
    u32 li = (i >> 4) * 17 + (i & 15);
    Qh32[base + i] = Ql[li];
    Kh32[base + i] = Kl[li];
  }
  // V: direct from Cd (ch 48..71); d==24 -> ones; 25..31 -> 0
  const u32* Cd32 = (const u32*)Cd;
  for (int i = t; i < 2048; i += 256) {
    int d = i >> 6, c = i & 63;
    u32 v32;
    if (d < 24)       v32 = Cd32[((48 + d) << 6) + c];
    else if (d == 24) v32 = 0x3F803F80u;   // bf16 1.0 pair -> denominator row
    else              v32 = 0u;
    Vt32[(((size_t)(h * 32 + d)) << 11) + (p0 >> 1) + c] = v32;
  }
}

// in-place exchange: a.lanes[32:63] <-> b.lanes[0:31]
__device__ __forceinline__ void swp32(u32& a, u32& b) {
  asm("v_permlane32_swap_b32 %0, %1" : "+v"(a), "+v"(b));
}

__device__ __forceinline__ bf16x8 mkfrag(u32 a, u32 b, u32 c, u32 d) {
  union { u32 u[4]; bf16x8 v; } x;
  x.u[0] = a; x.u[1] = b; x.u[2] = c; x.u[3] = d;
  return x.v;
}

#define MFMA32(A, B, C) __builtin_amdgcn_mfma_f32_32x32x16_bf16(A, B, C, 0, 0, 0)

// ---- K3: flash attention on 32x32x16 MFMAs. 512-thread blocks (8 waves = 8
// K-eighths of 512 keys); grid = 8 heads x 32 q-groups = 256 blocks (1/CU,
// head==XCD so K/V stay L2-resident). Per wave: 4 q-blocks of 32 q (128 q),
// register-resident S/P, zero global intermediates. R8 probe CONFIRMED this
// operating point: 64q/2-blocks-per-CU (4 waves/SIMD) regressed +2.7us --
// doubled K/V L2 traffic + halved per-wave ILP beat the extra TLP. 128q is
// the measured optimum in both directions.
//   QK^T: A=K-tile (32k x 16d chunk), B=Q -> S^T frag: col=q=lane&31,
//   row(reg)=key (reg&3)+8*(reg>>2)+4*(lane>>5). exp2 -> trunc-pack pairs
//   (consecutive keys) -> 2 v_permlane32_swap_b32 per 32-key group yields
//   key-LINEAR PV A-frags, so V needs no permutation.
//   PV: B=V^T[d][keys]; C col=d=lane&31; ones-row d=24 = denominator.
// s_setprio(1) around MFMA clusters (T5). Epilogue: two 64-row passes; Sf row
// stride 29 floats (gcd(29,32)=1 -> <=2-way bank conflicts). ----
__global__ __launch_bounds__(512, 2) void attn(const u16* __restrict__ Qh,
                                               const u16* __restrict__ Kh,
                                               const u16* __restrict__ Vt,
                                               u16* __restrict__ Pt) {
  __shared__ float Sf[8 * 64 * 29];  // 59392 B epilogue staging (per pass)
  __shared__ u16 Pb[64 * 24];        // 3072 B bf16 out staging
  int tid = threadIdx.x;
  int wave = tid >> 6, lane = tid & 63;
  int l31 = lane & 31, h5 = lane >> 5;
  int b = blockIdx.x;
  int head = b & 7;              // head == XCD (round-robin) -> K/V L2-resident
  int q0 = (b >> 3) << 7;        // 128 queries per block

  const u16* Kb = Kh + ((size_t)head << 17);
  const u16* Vb = Vt + ((size_t)head << 17);

  // Q as B-operand: per q-block of 32 q, two K=16 d-chunks (d24..31 are zero)
  size_t qbase = ((size_t)head << 12) + q0;
  bf16x8 qf[4][2];
  #pragma unroll
  for (int qb = 0; qb < 4; ++qb)
    #pragma unroll
    for (int c = 0; c < 2; ++c)
      qf[qb][c] = *(const bf16x8*)(Qh + ((qbase + qb * 32 + l31) << 5) +
                                   c * 16 + h5 * 8);

  f32x16 oC[4] = {};               // 32q x 32d per q-block (col 24 = denom)

  int kbase = wave << 9;           // 512 keys per wave

  for (int it = 0; it < 8; ++it) { // 8 tiles of 64 keys
    int k0 = kbase + it * 64;
    bf16x8 kf[2][2], vf[4];
    #pragma unroll
    for (int g = 0; g < 2; ++g)
      #pragma unroll
      for (int c = 0; c < 2; ++c)
        kf[g][c] = *(const bf16x8*)(Kb + (((size_t)(k0 + g * 32 + l31)) << 5) +
                                    c * 16 + h5 * 8);
    #pragma unroll
    for (int c4 = 0; c4 < 4; ++c4)
      vf[c4] = *(const bf16x8*)(Vb + (((size_t)l31) << 12) + k0 + c4 * 16 +
                                h5 * 8);
    #pragma unroll
    for (int qb = 0; qb < 4; ++qb) {
      __builtin_amdgcn_s_setprio(1);
      f32x16 s0{}, s1{};
      s0 = MFMA32(kf[0][0], qf[qb][0], s0);
      s0 = MFMA32(kf[0][1], qf[qb][1], s0);
      s1 = MFMA32(kf[1][0], qf[qb][0], s1);
      s1 = MFMA32(kf[1][1], qf[qb][1], s1);
      __builtin_amdgcn_s_setprio(0);
      // exp2 + truncate-pack consecutive-key pairs into u32 words
      u32 w[16];
      #pragma unroll
      for (int r = 0; r < 8; ++r) {
        u32 e0 = __float_as_uint(__builtin_amdgcn_exp2f(s0[2 * r]));
        u32 e1 = __float_as_uint(__builtin_amdgcn_exp2f(s0[2 * r + 1]));
        w[r] = __builtin_amdgcn_perm(e1, e0, 0x07060302u);
        u32 e2 = __float_as_uint(__builtin_amdgcn_exp2f(s1[2 * r]));
        u32 e3 = __float_as_uint(__builtin_amdgcn_exp2f(s1[2 * r + 1]));
        w[8 + r] = __builtin_amdgcn_perm(e3, e2, 0x07060302u);
      }
      // 2 swaps per 32-key group -> key-linear A-frags (chunks of 16 keys)
      swp32(w[0], w[2]);   swp32(w[1], w[3]);
      swp32(w[4], w[6]);   swp32(w[5], w[7]);
      swp32(w[8], w[10]);  swp32(w[9], w[11]);
      swp32(w[12], w[14]); swp32(w[13], w[15]);
      __builtin_amdgcn_s_setprio(1);
      oC[qb] = MFMA32(mkfrag(w[0], w[1], w[2], w[3]), vf[0], oC[qb]);
      oC[qb] = MFMA32(mkfrag(w[4], w[5], w[6], w[7]), vf[1], oC[qb]);
      oC[qb] = MFMA32(mkfrag(w[8], w[9], w[10], w[11]), vf[2], oC[qb]);
      oC[qb] = MFMA32(mkfrag(w[12], w[13], w[14], w[15]), vf[3], oC[qb]);
      __builtin_amdgcn_s_setprio(0);
    }
  }

  // epilogue: two 64-row passes (q-blocks 0..1, then 2..3).
  const u32* Pb32 = (const u32*)Pb;
  u32* Pt32 = (u32*)Pt;
  #pragma unroll
  for (int pass = 0; pass < 2; ++pass) {
    // stage fp32 C-layout (num cols 0..23, den col 24) into OWN strip
    int sb = wave * (64 * 29);
    #pragma unroll
    for (int qq = 0; qq < 2; ++qq) {
      int qb = pass * 2 + qq;
      #pragma unroll
      for (int r = 0; r < 16; ++r) {
        int row = qq * 32 + (r & 3) + 8 * (r >> 2) + 4 * h5;
        if (l31 < 25) Sf[sb + row * 29 + l31] = oC[qb][r];
      }
    }
    __syncthreads();   // staging complete (and, pass 1: prior Pb reads complete)
    // reduce the 8 K-eighths, normalize, stage bf16 per-pixel rows
    int q = tid & 63;
    int d0 = tid >> 6;             // 0..7
    int base0 = q * 29;
    const int SS = 64 * 29;
    float den = 0.f;
    #pragma unroll
    for (int s = 0; s < 8; ++s) den += Sf[base0 + s * SS + 24];
    float inv = 1.0f / den;
    #pragma unroll
    for (int dp = 0; dp < 3; ++dp) {
      int dd = dp * 8 + d0;
      float v = 0.f;
      #pragma unroll
      for (int s = 0; s < 8; ++s) v += Sf[base0 + s * SS + dd];
      Pb[q * 24 + dd] = f2bf(v * inv);
    }
    __syncthreads();   // Pb complete; Sf reads complete (safe to restage)
    // coalesced u32 stores of this pass's [64 px][12 u32] strip
    for (int i = tid; i < 768; i += 512) {
      int qq = i / 12, j = i - qq * 12;
      Pt32[(size_t)(q0 + pass * 64 + qq) * 96 + head * 12 + j] = Pb32[qq * 12 + j];
    }
  }
}

extern "C" void kernel_launch(void* const* d_in, const int* in_sizes, int n_in,
                              void* d_out, int out_size, void* d_ws, size_t ws_size,
                              hipStream_t stream) {
  const float* x      = (const float*)d_in[0];  // [192][4096]
  const float* w_qkv  = (const float*)d_in[1];  // [576][192]
  const float* w_dw   = (const float*)d_in[2];  // [576][9]
  const float* w_proj = (const float*)d_in[3];  // [192][192]
  float* out = (float*)d_out;                   // [192][4096] fp32

  char* ws = (char*)d_ws;
  u16*   qkv    = (u16*)  (ws);                 // 4718592 bf16 (dead after dwnv)
  u16*   Qh     = (u16*)  (ws + 18874368);      // 2097152
  u16*   Kh     = (u16*)  (ws + 20971520);      // 2097152
  u16*   Vt     = (u16*)  (ws + 23068672);      // 2097152  (end 25165824)
  u16*   Xt     = (u16*)  (ws + 25165824);      // 1572864  (bf16 X^T)
  u16*   Wb     = (u16*)  (ws + 26738688);      // 221184
  u16*   Wpb    = (u16*)  (ws + 26959872);      // 73728    (end 27033600)
  u16*   Pt     = (u16*)  (ws + 13107200);      // 1572864  (bf16 attn-out^T)

  // prep: X transpose->bf16 (128) + w_qkv->bf16 (54) + w_proj->bf16 (18)
  prep<<<dim3(200), 256, 0, stream>>>(x, w_qkv, w_proj, Xt, Wb, Wpb);
  // qkv GEMM on MFMA, bf16 out: grid (32 n-tiles, 18 m-tiles)
  mqkv<true><<<dim3(32, 18), 256, 0, stream>>>(Wb, Xt, qkv);
  // FUSED depthwise 3x3 + normalize + pack (spill-safe octet conv via LDS)
  dwnv<<<dim3(256), 256, 0, stream>>>(qkv, w_dw, (u32*)Qh, (u32*)Kh, (u32*)Vt);
  // 256 blocks x 512 threads (1/CU); 4 q-blocks of 32q per wave, 32x32x16 MFMAs
  attn<<<dim3(256), 512, 0, stream>>>(Qh, Kh, Vt, Pt);
  // proj GEMM on MFMA, fp32 out: grid (32 n-tiles, 6 m-tiles)
  mqkv<false><<<dim3(32, 6), 256, 0, stream>>>(Wpb, Pt, out);
}